// Round 9
// baseline (175.240 us; speedup 1.0000x reference)
//
#include <hip/hip_runtime.h>

// Problem constants
#define Jd   128   // feature dim
#define Cn   512   // num classes
#define TLn  16    // label seq length
#define Bn   32    // batch

// ---------------------------------------------------------------------------
// Reduction (x, lens dead; batch-uniform trajectory):
//   LT [tau][k][c] = L[c,tau,k]          l2T[tau][c] = ||L[c,tau,:]||^2
//   PLT[tau][j][c] = sum_k W[k][j]*L[c,tau,k]          ( = (L@W)^T )
//   S0[c]          = ||sos@W - L[c,0,:]||^2
//   DOT[s][tau][c] = l2T[tau][c] - 2*sum_j PLT[tau][j][s]*LT[tau][j][c]
//   s_0 = argmin S0;  s_t = argmin_c sum_{tau<t} DOT[s_{t-1}][tau][c]
//   out = [ broadcast_B(s_16) | broadcast_B(PLT[:, :, s_15]) ]
// Round-8 lesson (3-point A/B over rounds 6/7/8): k_dot is latency-bound;
// wave count beats per-thread load amortization (513blk/8x4 = 46.6us worse
// than 1025blk/4x4 < 42us). This round: 2048 blocks, 2s x 4c microtile,
// __launch_bounds__(256,8) -> 32 waves/CU. VALU floor is 6.8us.
// ---------------------------------------------------------------------------

__device__ __forceinline__ unsigned int f2ord(float f) {
    unsigned int u = __float_as_uint(f);
    return (u & 0x80000000u) ? ~u : (u | 0x80000000u);   // monotone total order
}
__device__ __forceinline__ unsigned long long packkey(float v, int c) {
    return ((unsigned long long)f2ord(v) << 32) | (unsigned int)c;
}

// grid = 256 x 256: bid -> tau = bid&15, c0 = (bid>>4)*32.
// Phase A: stage 32 L-rows -> LDS (coalesced), emit LT + l2T.
// Phase B: PLT for this (tau, 32-c) tile from LDS Ls x LDS-staged W strips.
__global__ void k_prep2(const float* __restrict__ L, const float* __restrict__ W,
                        float* __restrict__ LT, float* __restrict__ l2T,
                        float* __restrict__ PLT) {
    __shared__ float Ls[32][132];                // 16.9 KB (+4 pad, 16B-aligned rows)
    __shared__ float Ws[32][128];                // 16 KB k-strip of W
    int tid = threadIdx.x, bid = blockIdx.x;
    int tau = bid & 15, c0 = (bid >> 4) * 32;

    // --- Phase A ---
    int r = tid >> 3, o = tid & 7;               // row 0..31, octant
    const float4* src = (const float4*)(L + ((size_t)(c0 + r) * TLn + tau) * Jd);
    float l2p = 0.f;
    #pragma unroll
    for (int i = 0; i < 4; ++i) {
        float4 v = src[o * 4 + i];
        *(float4*)&Ls[r][(o * 4 + i) * 4] = v;
        l2p += v.x * v.x + v.y * v.y + v.z * v.z + v.w * v.w;
    }
    l2p += __shfl_xor(l2p, 1, 64);
    l2p += __shfl_xor(l2p, 2, 64);
    l2p += __shfl_xor(l2p, 4, 64);
    if (o == 0) l2T[tau * Cn + c0 + r] = l2p;
    __syncthreads();
    int cc = tid & 31, jg = tid >> 5;
    #pragma unroll
    for (int j = jg; j < Jd; j += 8)             // 128B-contiguous chunks
        LT[((size_t)tau * Jd + j) * Cn + c0 + cc] = Ls[cc][j];

    // --- Phase B: PLT[tau][j][c0+ch] = sum_k Ls[ch][k] * W[k][j] ---
    int ch = tid & 31, jh = tid >> 5;            // c lane, 8 j-groups
    float acc[4][4] = {};                        // [j-strip it][j-quad u]
    for (int kb = 0; kb < 4; ++kb) {
        __syncthreads();                         // protect Ws reuse
        int kk = tid >> 3, oo = tid & 7;
        const float4* wsrc = (const float4*)(W + (size_t)(kb * 32 + kk) * Jd);
        #pragma unroll
        for (int i = 0; i < 4; ++i)
            *(float4*)&Ws[kk][(oo * 4 + i) * 4] = wsrc[oo * 4 + i];
        __syncthreads();
        #pragma unroll 8
        for (int k = 0; k < 32; ++k) {
            float lv = Ls[ch][kb * 32 + k];      // 4-way conflict (pad 132) - ok
            #pragma unroll
            for (int it = 0; it < 4; ++it) {
                float4 wv = *(const float4*)&Ws[k][it * 32 + jh * 4]; // broadcast
                acc[it][0] = fmaf(lv, wv.x, acc[it][0]);
                acc[it][1] = fmaf(lv, wv.y, acc[it][1]);
                acc[it][2] = fmaf(lv, wv.z, acc[it][2]);
                acc[it][3] = fmaf(lv, wv.w, acc[it][3]);
            }
        }
    }
    #pragma unroll
    for (int it = 0; it < 4; ++it)
        #pragma unroll
        for (int u = 0; u < 4; ++u) {            // 128B-contiguous chunks
            int j = it * 32 + jh * 4 + u;
            PLT[((size_t)tau * Jd + j) * Cn + c0 + ch] = acc[it][u];
        }
}

// grid = 2049 x 256, 8 blocks/CU (32 waves/CU). bid<2048: tau = bid&15,
// st = (bid>>4)&15 (32 s), cq = bid>>8 (64 c). Microtile 2s x 4c:
// a float2 (broadcast) + b float4 (coalesced) per j, 8 FMA. bid==2048: S0.
__global__ void __launch_bounds__(256, 8)
k_dot(const float* __restrict__ LT, const float* __restrict__ PLT,
      const float* __restrict__ l2T,
      const float* __restrict__ sos, const float* __restrict__ W,
      float* __restrict__ DOT, float* __restrict__ S0) {
    int tid = threadIdx.x, bid = blockIdx.x;

    if (bid == 2048) {                           // ---- S0 path ----
        __shared__ float pred0[Jd];
        if (tid < Jd) {
            float a = 0.f;
            for (int k = 0; k < Jd; ++k) a = fmaf(sos[k], W[k * Jd + tid], a);
            pred0[tid] = a;
        }
        __syncthreads();
        float a0 = 0.f, a1 = 0.f;
        for (int jj = 0; jj < Jd; ++jj) {
            float p = pred0[jj];
            float d0 = p - LT[(size_t)jj * Cn + tid];        // tau = 0 plane
            float d1 = p - LT[(size_t)jj * Cn + tid + 256];
            a0 = fmaf(d0, d0, a0);
            a1 = fmaf(d1, d1, a1);
        }
        S0[tid] = a0;  S0[tid + 256] = a1;
        return;
    }

    int tau = bid & 15, st = (bid >> 4) & 15, cq = bid >> 8;
    int cg = tid & 15, sh = tid >> 4;
    int c = cq * 64 + cg * 4, s = st * 32 + sh * 2;
    const float* Bp = LT  + (size_t)tau * Jd * Cn + c;
    const float* Ap = PLT + (size_t)tau * Jd * Cn + s;
    float acc[2][4] = {};
    #pragma unroll 4
    for (int jj = 0; jj < Jd; ++jj) {
        float4 b = *(const float4*)(Bp + (size_t)jj * Cn);   // coalesced 256B/wave
        float2 a = *(const float2*)(Ap + (size_t)jj * Cn);   // 16-lane broadcast
        acc[0][0] = fmaf(a.x, b.x, acc[0][0]);
        acc[0][1] = fmaf(a.x, b.y, acc[0][1]);
        acc[0][2] = fmaf(a.x, b.z, acc[0][2]);
        acc[0][3] = fmaf(a.x, b.w, acc[0][3]);
        acc[1][0] = fmaf(a.y, b.x, acc[1][0]);
        acc[1][1] = fmaf(a.y, b.y, acc[1][1]);
        acc[1][2] = fmaf(a.y, b.z, acc[1][2]);
        acc[1][3] = fmaf(a.y, b.w, acc[1][3]);
    }
    float4 l2v = *(const float4*)(l2T + tau * Cn + c);
    #pragma unroll
    for (int i = 0; i < 2; ++i) {
        float4 v = {l2v.x - 2.f * acc[i][0], l2v.y - 2.f * acc[i][1],
                    l2v.z - 2.f * acc[i][2], l2v.w - 2.f * acc[i][3]};
        *(float4*)(DOT + ((size_t)(s + i) * TLn + tau) * Cn + c) = v;  // coalesced
    }
}

// 1 block x 256: 17-step argmin chain (32 loads in flight per step, mask-FMA)
// + fused output write (8 gather loads in flight, then coalesced 256B stores).
__global__ void k_fin(const float* __restrict__ S0, const float* __restrict__ DOT,
                      const float* __restrict__ PLT, float* __restrict__ out) {
    __shared__ unsigned long long red[4];
    __shared__ int sCur;
    __shared__ int keys[TLn + 1];
    int tid = threadIdx.x, w = tid >> 6, lane = tid & 63;

    for (int t = 0; t <= TLn; ++t) {
        float sum0, sum1;
        if (t == 0) {
            sum0 = S0[tid];  sum1 = S0[tid + 256];
        } else {
            const float* base = DOT + (size_t)sCur * TLn * Cn;
            float v0[TLn], v1[TLn];
            #pragma unroll
            for (int tau = 0; tau < TLn; ++tau) {            // 32 independent loads
                v0[tau] = base[(size_t)tau * Cn + tid];
                v1[tau] = base[(size_t)tau * Cn + tid + 256];
            }
            sum0 = sum1 = 0.f;
            #pragma unroll
            for (int tau = 0; tau < TLn; ++tau) {
                float m = (tau < t) ? 1.f : 0.f;
                sum0 = fmaf(v0[tau], m, sum0);
                sum1 = fmaf(v1[tau], m, sum1);
            }
        }
        unsigned long long m0 = packkey(sum0, tid);
        unsigned long long m1 = packkey(sum1, tid + 256);
        unsigned long long m = (m1 < m0) ? m1 : m0;
        for (int o = 32; o; o >>= 1) {
            unsigned long long o2 = __shfl_down(m, o, 64);
            if (o2 < m) m = o2;
        }
        if (lane == 0) red[w] = m;
        __syncthreads();
        if (tid == 0) {
            unsigned long long b = red[0];
            #pragma unroll
            for (int i = 1; i < 4; ++i) if (red[i] < b) b = red[i];
            int sv = (int)(b & 0xFFFFFFFFull);
            sCur = sv;  keys[t] = sv;
        }
        __syncthreads();
    }

    // ---- output: [sofar(32) | pls(B,TL,J)] ----
    int s16 = keys[TLn], s15 = keys[TLn - 1];
    float v[8];
    #pragma unroll
    for (int q = 0; q < 8; ++q)                  // 8 independent gathers in flight
        v[q] = PLT[(size_t)(q * 256 + tid) * Cn + s15];
    if (tid < Bn) out[tid] = (float)s16;
    #pragma unroll
    for (int q = 0; q < 8; ++q)
        for (int b = 0; b < Bn; ++b)             // 256B contiguous per store inst
            out[Bn + (size_t)b * (TLn * Jd) + q * 256 + tid] = v[q];
}

extern "C" void kernel_launch(void* const* d_in, const int* in_sizes, int n_in,
                              void* d_out, int out_size, void* d_ws, size_t ws_size,
                              hipStream_t stream) {
    // inputs: 0:x (dead, 32MB), 1:lens (dead), 2:sos, 3:label_seqs, 4:W  (all f32)
    const float* sos = (const float*)d_in[2];
    const float* L   = (const float*)d_in[3];
    const float* W   = (const float*)d_in[4];
    float* out = (float*)d_out;

    // ws: S0(2KB)@0 | l2T(32KB)@4K | PLT(4MB)@64K | LT(4MB) | DOT(16.8MB)
    const size_t l2Off  = 4096;
    const size_t pltOff = 65536;
    const size_t ltOff  = pltOff + (size_t)TLn * Jd * Cn * sizeof(float);
    const size_t dotOff = ltOff  + (size_t)TLn * Jd * Cn * sizeof(float);
    const size_t need   = dotOff + (size_t)Cn * TLn * Cn * sizeof(float);  // ~25 MB
    char* base = (ws_size >= need) ? (char*)d_ws : (char*)d_in[0];  // x dead, 32 MB
    float* S0   = (float*)base;
    float* l2T  = (float*)(base + l2Off);
    float* PLT  = (float*)(base + pltOff);
    float* LT   = (float*)(base + ltOff);
    float* DOT  = (float*)(base + dotOff);

    hipLaunchKernelGGL(k_prep2, dim3(256),  dim3(256), 0, stream, L, W, LT, l2T, PLT);
    hipLaunchKernelGGL(k_dot,   dim3(2049), dim3(256), 0, stream,
                       LT, PLT, l2T, sos, W, DOT, S0);
    hipLaunchKernelGGL(k_fin,   dim3(1),    dim3(256), 0, stream, S0, DOT, PLT, out);
}

// Round 10
// 128.955 us; speedup vs baseline: 1.3589x; 1.3589x over previous
//
#include <hip/hip_runtime.h>

// Problem constants
#define Jd   128   // feature dim
#define Cn   512   // num classes
#define TLn  16    // label seq length
#define Bn   32    // batch

// ---------------------------------------------------------------------------
// Reduction (x, lens dead; batch-uniform trajectory):
//   LT [tau][k][c] = L[c,tau,k]          l2T[tau][c] = ||L[c,tau,:]||^2
//   PLT[tau][j][c] = sum_k W[k][j]*L[c,tau,k]          ( = (L@W)^T )
//   S0[c]          = ||sos@W - L[c,0,:]||^2
//   DOT[s][tau][c] = l2T[tau][c] - 2*sum_j PLT[tau][j][s]*LT[tau][j][c]
//   s_0 = argmin S0;  s_t = argmin_c sum_{tau<t} DOT[s_{t-1}][tau][c]
//   out = [ broadcast_B(s_16) | broadcast_B(PLT[:, :, s_15]) ]
// Round-9 lesson (r7/r8/r9 3-point): k_dot time tracks global-load instruction
// count, not occupancy (occ 57% made it WORSE: deeper VMEM queue, L1 thrash).
// Fix: classic LDS-staged GEMM. LT/PLT are already [j][c] -> staging is a
// straight coalesced copy (NO transpose, zero-conflict LDS writes; this is
// what round-4's LDS attempt got wrong). Tile 64s x 128c, K in 2 j-halves
// (48 KB LDS), micro 4s x 8c: 3 ds_reads / 32 FMA -> VALU-bound by design.
// ---------------------------------------------------------------------------

__device__ __forceinline__ unsigned int f2ord(float f) {
    unsigned int u = __float_as_uint(f);
    return (u & 0x80000000u) ? ~u : (u | 0x80000000u);   // monotone total order
}
__device__ __forceinline__ unsigned long long packkey(float v, int c) {
    return ((unsigned long long)f2ord(v) << 32) | (unsigned int)c;
}

// grid = 256 x 256: bid -> tau = bid&15, c0 = (bid>>4)*32.
// Phase A: stage 32 L-rows -> LDS (coalesced), emit LT + l2T.
// Phase B: PLT for this (tau, 32-c) tile from LDS Ls x LDS-staged W strips.
__global__ void k_prep2(const float* __restrict__ L, const float* __restrict__ W,
                        float* __restrict__ LT, float* __restrict__ l2T,
                        float* __restrict__ PLT) {
    __shared__ float Ls[32][132];                // 16.9 KB (+4 pad, 16B-aligned rows)
    __shared__ float Ws[32][128];                // 16 KB k-strip of W
    int tid = threadIdx.x, bid = blockIdx.x;
    int tau = bid & 15, c0 = (bid >> 4) * 32;

    // --- Phase A ---
    int r = tid >> 3, o = tid & 7;               // row 0..31, octant
    const float4* src = (const float4*)(L + ((size_t)(c0 + r) * TLn + tau) * Jd);
    float l2p = 0.f;
    #pragma unroll
    for (int i = 0; i < 4; ++i) {
        float4 v = src[o * 4 + i];
        *(float4*)&Ls[r][(o * 4 + i) * 4] = v;
        l2p += v.x * v.x + v.y * v.y + v.z * v.z + v.w * v.w;
    }
    l2p += __shfl_xor(l2p, 1, 64);
    l2p += __shfl_xor(l2p, 2, 64);
    l2p += __shfl_xor(l2p, 4, 64);
    if (o == 0) l2T[tau * Cn + c0 + r] = l2p;
    __syncthreads();
    int cc = tid & 31, jg = tid >> 5;
    #pragma unroll
    for (int j = jg; j < Jd; j += 8)             // 128B-contiguous chunks
        LT[((size_t)tau * Jd + j) * Cn + c0 + cc] = Ls[cc][j];

    // --- Phase B: PLT[tau][j][c0+ch] = sum_k Ls[ch][k] * W[k][j] ---
    int ch = tid & 31, jh = tid >> 5;            // c lane, 8 j-groups
    float acc[4][4] = {};                        // [j-strip it][j-quad u]
    for (int kb = 0; kb < 4; ++kb) {
        __syncthreads();                         // protect Ws reuse
        int kk = tid >> 3, oo = tid & 7;
        const float4* wsrc = (const float4*)(W + (size_t)(kb * 32 + kk) * Jd);
        #pragma unroll
        for (int i = 0; i < 4; ++i)
            *(float4*)&Ws[kk][(oo * 4 + i) * 4] = wsrc[oo * 4 + i];
        __syncthreads();
        #pragma unroll 8
        for (int k = 0; k < 32; ++k) {
            float lv = Ls[ch][kb * 32 + k];      // 4-way conflict (pad 132) - ok
            #pragma unroll
            for (int it = 0; it < 4; ++it) {
                float4 wv = *(const float4*)&Ws[k][it * 32 + jh * 4]; // broadcast
                acc[it][0] = fmaf(lv, wv.x, acc[it][0]);
                acc[it][1] = fmaf(lv, wv.y, acc[it][1]);
                acc[it][2] = fmaf(lv, wv.z, acc[it][2]);
                acc[it][3] = fmaf(lv, wv.w, acc[it][3]);
            }
        }
    }
    #pragma unroll
    for (int it = 0; it < 4; ++it)
        #pragma unroll
        for (int u = 0; u < 4; ++u) {            // 128B-contiguous chunks
            int j = it * 32 + jh * 4 + u;
            PLT[((size_t)tau * Jd + j) * Cn + c0 + ch] = acc[it][u];
        }
}

// grid = 513 x 256, LDS-staged GEMM. bid<512: tau = bid&15, st = (bid>>4)&7
// (64 s), cq = bid>>7 (128 c). K split in 2 j-halves; micro 4s x 8c.
// bid==512: S0.
__global__ void __launch_bounds__(256, 2)
k_dot(const float* __restrict__ LT, const float* __restrict__ PLT,
      const float* __restrict__ l2T,
      const float* __restrict__ sos, const float* __restrict__ W,
      float* __restrict__ DOT, float* __restrict__ S0) {
    __shared__ float As[64][64];                 // 16 KB  [j][s]
    __shared__ float Bs[64][128];                // 32 KB  [j][c]
    int tid = threadIdx.x, bid = blockIdx.x;

    if (bid == 512) {                            // ---- S0 path ----
        float* pred0 = &As[0][0];
        if (tid < Jd) {
            float a = 0.f;
            for (int k = 0; k < Jd; ++k) a = fmaf(sos[k], W[k * Jd + tid], a);
            pred0[tid] = a;
        }
        __syncthreads();
        float a0 = 0.f, a1 = 0.f;
        for (int jj = 0; jj < Jd; ++jj) {
            float p = pred0[jj];
            float d0 = p - LT[(size_t)jj * Cn + tid];        // tau = 0 plane
            float d1 = p - LT[(size_t)jj * Cn + tid + 256];
            a0 = fmaf(d0, d0, a0);
            a1 = fmaf(d1, d1, a1);
        }
        S0[tid] = a0;  S0[tid + 256] = a1;
        return;
    }

    int tau = bid & 15, st = (bid >> 4) & 7, cq = bid >> 7;
    int s0 = st * 64, c0 = cq * 128;
    int sg = tid >> 4, cg = tid & 15;            // 16x16 threads

    float acc[4][8] = {};                        // 4 s x (4+4) c
    for (int h = 0; h < 2; ++h) {                // j-halves
        __syncthreads();
        // stage A half: 64 j-rows x 64 s  (coalesced global, conflict-free LDS)
        const float4* Asrc = (const float4*)(PLT + ((size_t)tau * Jd + h * 64) * Cn + s0);
        #pragma unroll
        for (int i = 0; i < 4; ++i) {
            int flat = i * 256 + tid;            // 0..1023 float4s
            int row = flat >> 4, col = flat & 15;
            *(float4*)&As[row][col * 4] = Asrc[(size_t)row * (Cn / 4) + col];
        }
        // stage B half: 64 j-rows x 128 c
        const float4* Bsrc = (const float4*)(LT + ((size_t)tau * Jd + h * 64) * Cn + c0);
        #pragma unroll
        for (int i = 0; i < 8; ++i) {
            int flat = i * 256 + tid;            // 0..2047 float4s
            int row = flat >> 5, col = flat & 31;
            *(float4*)&Bs[row][col * 4] = Bsrc[(size_t)row * (Cn / 4) + col];
        }
        __syncthreads();
        #pragma unroll 4
        for (int j = 0; j < 64; ++j) {           // ascending j: same sum order
            float4 a  = *(const float4*)&As[j][sg * 4];       // broadcast, no conflict
            float4 b0 = *(const float4*)&Bs[j][cg * 4];       // 2-way (free)
            float4 b1 = *(const float4*)&Bs[j][64 + cg * 4];  // 2-way (free)
            float av[4] = {a.x, a.y, a.z, a.w};
            float bv[8] = {b0.x, b0.y, b0.z, b0.w, b1.x, b1.y, b1.z, b1.w};
            #pragma unroll
            for (int i = 0; i < 4; ++i)
                #pragma unroll
                for (int q = 0; q < 8; ++q)
                    acc[i][q] = fmaf(av[i], bv[q], acc[i][q]);
        }
    }

    float4 l2a = *(const float4*)(l2T + tau * Cn + c0 + cg * 4);
    float4 l2b = *(const float4*)(l2T + tau * Cn + c0 + 64 + cg * 4);
    #pragma unroll
    for (int i = 0; i < 4; ++i) {
        int s = s0 + sg * 4 + i;
        float* dst = DOT + ((size_t)s * TLn + tau) * Cn + c0;
        float4 v0 = {l2a.x - 2.f * acc[i][0], l2a.y - 2.f * acc[i][1],
                     l2a.z - 2.f * acc[i][2], l2a.w - 2.f * acc[i][3]};
        float4 v1 = {l2b.x - 2.f * acc[i][4], l2b.y - 2.f * acc[i][5],
                     l2b.z - 2.f * acc[i][6], l2b.w - 2.f * acc[i][7]};
        *(float4*)(dst + cg * 4) = v0;           // 256B contiguous per 16 lanes
        *(float4*)(dst + 64 + cg * 4) = v1;
    }
}

// 1 block x 256: 17-step argmin chain (32 loads in flight per step, mask-FMA)
// + fused output write (8 gather loads in flight, then coalesced 256B stores).
__global__ void k_fin(const float* __restrict__ S0, const float* __restrict__ DOT,
                      const float* __restrict__ PLT, float* __restrict__ out) {
    __shared__ unsigned long long red[4];
    __shared__ int sCur;
    __shared__ int keys[TLn + 1];
    int tid = threadIdx.x, w = tid >> 6, lane = tid & 63;

    for (int t = 0; t <= TLn; ++t) {
        float sum0, sum1;
        if (t == 0) {
            sum0 = S0[tid];  sum1 = S0[tid + 256];
        } else {
            const float* base = DOT + (size_t)sCur * TLn * Cn;
            float v0[TLn], v1[TLn];
            #pragma unroll
            for (int tau = 0; tau < TLn; ++tau) {            // 32 independent loads
                v0[tau] = base[(size_t)tau * Cn + tid];
                v1[tau] = base[(size_t)tau * Cn + tid + 256];
            }
            sum0 = sum1 = 0.f;
            #pragma unroll
            for (int tau = 0; tau < TLn; ++tau) {
                float m = (tau < t) ? 1.f : 0.f;
                sum0 = fmaf(v0[tau], m, sum0);
                sum1 = fmaf(v1[tau], m, sum1);
            }
        }
        unsigned long long m0 = packkey(sum0, tid);
        unsigned long long m1 = packkey(sum1, tid + 256);
        unsigned long long m = (m1 < m0) ? m1 : m0;
        for (int o = 32; o; o >>= 1) {
            unsigned long long o2 = __shfl_down(m, o, 64);
            if (o2 < m) m = o2;
        }
        if (lane == 0) red[w] = m;
        __syncthreads();
        if (tid == 0) {
            unsigned long long b = red[0];
            #pragma unroll
            for (int i = 1; i < 4; ++i) if (red[i] < b) b = red[i];
            int sv = (int)(b & 0xFFFFFFFFull);
            sCur = sv;  keys[t] = sv;
        }
        __syncthreads();
    }

    // ---- output: [sofar(32) | pls(B,TL,J)] ----
    int s16 = keys[TLn], s15 = keys[TLn - 1];
    float v[8];
    #pragma unroll
    for (int q = 0; q < 8; ++q)                  // 8 independent gathers in flight
        v[q] = PLT[(size_t)(q * 256 + tid) * Cn + s15];
    if (tid < Bn) out[tid] = (float)s16;
    #pragma unroll
    for (int q = 0; q < 8; ++q)
        for (int b = 0; b < Bn; ++b)             // 256B contiguous per store inst
            out[Bn + (size_t)b * (TLn * Jd) + q * 256 + tid] = v[q];
}

extern "C" void kernel_launch(void* const* d_in, const int* in_sizes, int n_in,
                              void* d_out, int out_size, void* d_ws, size_t ws_size,
                              hipStream_t stream) {
    // inputs: 0:x (dead, 32MB), 1:lens (dead), 2:sos, 3:label_seqs, 4:W  (all f32)
    const float* sos = (const float*)d_in[2];
    const float* L   = (const float*)d_in[3];
    const float* W   = (const float*)d_in[4];
    float* out = (float*)d_out;

    // ws: S0(2KB)@0 | l2T(32KB)@4K | PLT(4MB)@64K | LT(4MB) | DOT(16.8MB)
    const size_t l2Off  = 4096;
    const size_t pltOff = 65536;
    const size_t ltOff  = pltOff + (size_t)TLn * Jd * Cn * sizeof(float);
    const size_t dotOff = ltOff  + (size_t)TLn * Jd * Cn * sizeof(float);
    const size_t need   = dotOff + (size_t)Cn * TLn * Cn * sizeof(float);  // ~25 MB
    char* base = (ws_size >= need) ? (char*)d_ws : (char*)d_in[0];  // x dead, 32 MB
    float* S0   = (float*)base;
    float* l2T  = (float*)(base + l2Off);
    float* PLT  = (float*)(base + pltOff);
    float* LT   = (float*)(base + ltOff);
    float* DOT  = (float*)(base + dotOff);

    hipLaunchKernelGGL(k_prep2, dim3(256), dim3(256), 0, stream, L, W, LT, l2T, PLT);
    hipLaunchKernelGGL(k_dot,   dim3(513), dim3(256), 0, stream,
                       LT, PLT, l2T, sos, W, DOT, S0);
    hipLaunchKernelGGL(k_fin,   dim3(1),   dim3(256), 0, stream, S0, DOT, PLT, out);
}

// Round 11
// 125.086 us; speedup vs baseline: 1.4010x; 1.0309x over previous
//
#include <hip/hip_runtime.h>

// Problem constants
#define Jd   128   // feature dim
#define Cn   512   // num classes
#define TLn  16    // label seq length
#define Bn   32    // batch

// ---------------------------------------------------------------------------
// Reduction (x, lens dead; batch-uniform trajectory):
//   LT [tau][k][c] = L[c,tau,k]          l2T[tau][c] = ||L[c,tau,:]||^2
//   PLT[tau][j][c] = sum_k W[k][j]*L[c,tau,k]          ( = (L@W)^T )
//   S0[c]          = ||sos@W - L[c,0,:]||^2
//   DOT[s][tau][c] = l2T[tau][c] - 2*sum_j PLT[tau][j][s]*LT[tau][j][c]
//   s_0 = argmin S0;  s_t = argmin_c sum_{tau<t} DOT[s_{t-1}][tau][c]
//   out = [ broadcast_B(s_16) | broadcast_B(PLT[:, :, s_15]) ]
// Round-10 accounting: k_prep2 (256 blocks = 1 block/CU, 1 wave/SIMD) was
// ~20-30us: its 5-LDS-reads-per-16-FMA inner loop had NO co-resident waves to
// hide ~120cyc DS latency. k_prep3: 512 blocks (3/CU via 52KB LDS, 12
// waves/CU), conflict-free b32 a-reads (pitch-36 transposed tile), broadcast
// b128 w-reads from LDS-staged W half, all global stores 128B-contiguous.
// K ascending -> bit-identical DOT -> absmax 0 preserved.
// ---------------------------------------------------------------------------

__device__ __forceinline__ unsigned int f2ord(float f) {
    unsigned int u = __float_as_uint(f);
    return (u & 0x80000000u) ? ~u : (u | 0x80000000u);   // monotone total order
}
__device__ __forceinline__ unsigned long long packkey(float v, int c) {
    return ((unsigned long long)f2ord(v) << 32) | (unsigned int)c;
}

// grid = 512 x 256: bid -> tau = bid&15, jh = (bid>>4)&1 (j-half), ct = bid>>5
// (16 c-tiles of 32). Produces PLT[tau][jh*64..+63][c-tile]; jh==0 blocks also
// emit LT + l2T for their c-tile.
__global__ void __launch_bounds__(256, 4)
k_prep3(const float* __restrict__ L, const float* __restrict__ W,
        float* __restrict__ LT, float* __restrict__ l2T,
        float* __restrict__ PLT) {
    __shared__ float Lst[128][36];               // 18 KB transposed L tile [k][c]
    __shared__ float Ws[128][68];                // 34 KB W half [k][j-j0]
    int tid = threadIdx.x, bid = blockIdx.x;
    int tau = bid & 15, jh = (bid >> 4) & 1, c0 = (bid >> 5) * 32;
    int j0 = jh * 64;

    // --- stage Lst (transpose 32 L-rows; coalesced global reads) + l2 ---
    int cr = tid >> 3, oc = tid & 7;             // c-row 0..31, octant
    const float4* src = (const float4*)(L + ((size_t)(c0 + cr) * TLn + tau) * Jd);
    float l2p = 0.f;
    #pragma unroll
    for (int i = 0; i < 4; ++i) {
        float4 v = src[oc * 4 + i];
        int kb = (oc * 4 + i) * 4;
        Lst[kb + 0][cr] = v.x;  Lst[kb + 1][cr] = v.y;
        Lst[kb + 2][cr] = v.z;  Lst[kb + 3][cr] = v.w;
        l2p += v.x * v.x + v.y * v.y + v.z * v.z + v.w * v.w;
    }
    l2p += __shfl_down(l2p, 4, 8);               // reduce over octant (8 lanes/c)
    l2p += __shfl_down(l2p, 2, 8);
    l2p += __shfl_down(l2p, 1, 8);
    if (oc == 0 && jh == 0) l2T[tau * Cn + c0 + cr] = l2p;

    // --- stage Ws: W[k][j0..j0+63], straight coalesced copy ---
    #pragma unroll
    for (int r = 0; r < 8; ++r) {
        int idx = r * 256 + tid;                 // 0..2047 float4s
        int k = idx >> 4, f = idx & 15;
        *(float4*)&Ws[k][f * 4] = *(const float4*)(W + (size_t)k * Jd + j0 + f * 4);
    }
    __syncthreads();

    int c = tid & 31, jq = tid >> 5;             // c lane (coalesced), 8 j-groups

    // --- LT emit (jh==0 only): b32 reads conflict-free, 128B-chunk stores ---
    if (jh == 0) {
        #pragma unroll
        for (int k = jq; k < Jd; k += 8)
            LT[((size_t)tau * Jd + k) * Cn + c0 + c] = Lst[k][c];
    }

    // --- GEMM: PLT[tau][j0+jq*8+i][c0+c] = sum_k Ws[k][jq*8+i] * Lst[k][c] ---
    float acc[8] = {};
    #pragma unroll 4
    for (int k = 0; k < Jd; ++k) {               // ascending k: same sum order
        float a = Lst[k][c];                     // b32, banks all distinct (pitch 36)
        float4 w0 = *(const float4*)&Ws[k][jq * 8];      // 32-lane broadcast b128
        float4 w1 = *(const float4*)&Ws[k][jq * 8 + 4];
        acc[0] = fmaf(a, w0.x, acc[0]);
        acc[1] = fmaf(a, w0.y, acc[1]);
        acc[2] = fmaf(a, w0.z, acc[2]);
        acc[3] = fmaf(a, w0.w, acc[3]);
        acc[4] = fmaf(a, w1.x, acc[4]);
        acc[5] = fmaf(a, w1.y, acc[5]);
        acc[6] = fmaf(a, w1.z, acc[6]);
        acc[7] = fmaf(a, w1.w, acc[7]);
    }
    #pragma unroll
    for (int i = 0; i < 8; ++i)                  // two 128B chunks per store inst
        PLT[((size_t)tau * Jd + j0 + jq * 8 + i) * Cn + c0 + c] = acc[i];
}

// grid = 513 x 256, LDS-staged GEMM. bid<512: tau = bid&15, st = (bid>>4)&7
// (64 s), cq = bid>>7 (128 c). K split in 2 j-halves; micro 4s x 8c.
// bid==512: S0.
__global__ void __launch_bounds__(256, 2)
k_dot(const float* __restrict__ LT, const float* __restrict__ PLT,
      const float* __restrict__ l2T,
      const float* __restrict__ sos, const float* __restrict__ W,
      float* __restrict__ DOT, float* __restrict__ S0) {
    __shared__ float As[64][64];                 // 16 KB  [j][s]
    __shared__ float Bs[64][128];                // 32 KB  [j][c]
    int tid = threadIdx.x, bid = blockIdx.x;

    if (bid == 512) {                            // ---- S0 path ----
        float* pred0 = &As[0][0];
        if (tid < Jd) {
            float a = 0.f;
            for (int k = 0; k < Jd; ++k) a = fmaf(sos[k], W[k * Jd + tid], a);
            pred0[tid] = a;
        }
        __syncthreads();
        float a0 = 0.f, a1 = 0.f;
        for (int jj = 0; jj < Jd; ++jj) {
            float p = pred0[jj];
            float d0 = p - LT[(size_t)jj * Cn + tid];        // tau = 0 plane
            float d1 = p - LT[(size_t)jj * Cn + tid + 256];
            a0 = fmaf(d0, d0, a0);
            a1 = fmaf(d1, d1, a1);
        }
        S0[tid] = a0;  S0[tid + 256] = a1;
        return;
    }

    int tau = bid & 15, st = (bid >> 4) & 7, cq = bid >> 7;
    int s0 = st * 64, c0 = cq * 128;
    int sg = tid >> 4, cg = tid & 15;            // 16x16 threads

    float acc[4][8] = {};                        // 4 s x (4+4) c
    for (int h = 0; h < 2; ++h) {                // j-halves
        __syncthreads();
        // stage A half: 64 j-rows x 64 s  (coalesced global, conflict-free LDS)
        const float4* Asrc = (const float4*)(PLT + ((size_t)tau * Jd + h * 64) * Cn + s0);
        #pragma unroll
        for (int i = 0; i < 4; ++i) {
            int flat = i * 256 + tid;            // 0..1023 float4s
            int row = flat >> 4, col = flat & 15;
            *(float4*)&As[row][col * 4] = Asrc[(size_t)row * (Cn / 4) + col];
        }
        // stage B half: 64 j-rows x 128 c
        const float4* Bsrc = (const float4*)(LT + ((size_t)tau * Jd + h * 64) * Cn + c0);
        #pragma unroll
        for (int i = 0; i < 8; ++i) {
            int flat = i * 256 + tid;            // 0..2047 float4s
            int row = flat >> 5, col = flat & 31;
            *(float4*)&Bs[row][col * 4] = Bsrc[(size_t)row * (Cn / 4) + col];
        }
        __syncthreads();
        #pragma unroll 4
        for (int j = 0; j < 64; ++j) {           // ascending j: same sum order
            float4 a  = *(const float4*)&As[j][sg * 4];       // broadcast, no conflict
            float4 b0 = *(const float4*)&Bs[j][cg * 4];       // 2-way (free)
            float4 b1 = *(const float4*)&Bs[j][64 + cg * 4];  // 2-way (free)
            float av[4] = {a.x, a.y, a.z, a.w};
            float bv[8] = {b0.x, b0.y, b0.z, b0.w, b1.x, b1.y, b1.z, b1.w};
            #pragma unroll
            for (int i = 0; i < 4; ++i)
                #pragma unroll
                for (int q = 0; q < 8; ++q)
                    acc[i][q] = fmaf(av[i], bv[q], acc[i][q]);
        }
    }

    float4 l2a = *(const float4*)(l2T + tau * Cn + c0 + cg * 4);
    float4 l2b = *(const float4*)(l2T + tau * Cn + c0 + 64 + cg * 4);
    #pragma unroll
    for (int i = 0; i < 4; ++i) {
        int s = s0 + sg * 4 + i;
        float* dst = DOT + ((size_t)s * TLn + tau) * Cn + c0;
        float4 v0 = {l2a.x - 2.f * acc[i][0], l2a.y - 2.f * acc[i][1],
                     l2a.z - 2.f * acc[i][2], l2a.w - 2.f * acc[i][3]};
        float4 v1 = {l2b.x - 2.f * acc[i][4], l2b.y - 2.f * acc[i][5],
                     l2b.z - 2.f * acc[i][6], l2b.w - 2.f * acc[i][7]};
        *(float4*)(dst + cg * 4) = v0;           // 256B contiguous per 16 lanes
        *(float4*)(dst + 64 + cg * 4) = v1;
    }
}

// 1 block x 256: 17-step argmin chain (32 loads in flight per step, mask-FMA)
// + fused output write (8 gather loads in flight, then coalesced 256B stores).
__global__ void k_fin(const float* __restrict__ S0, const float* __restrict__ DOT,
                      const float* __restrict__ PLT, float* __restrict__ out) {
    __shared__ unsigned long long red[4];
    __shared__ int sCur;
    __shared__ int keys[TLn + 1];
    int tid = threadIdx.x, w = tid >> 6, lane = tid & 63;

    for (int t = 0; t <= TLn; ++t) {
        float sum0, sum1;
        if (t == 0) {
            sum0 = S0[tid];  sum1 = S0[tid + 256];
        } else {
            const float* base = DOT + (size_t)sCur * TLn * Cn;
            float v0[TLn], v1[TLn];
            #pragma unroll
            for (int tau = 0; tau < TLn; ++tau) {            // 32 independent loads
                v0[tau] = base[(size_t)tau * Cn + tid];
                v1[tau] = base[(size_t)tau * Cn + tid + 256];
            }
            sum0 = sum1 = 0.f;
            #pragma unroll
            for (int tau = 0; tau < TLn; ++tau) {
                float m = (tau < t) ? 1.f : 0.f;
                sum0 = fmaf(v0[tau], m, sum0);
                sum1 = fmaf(v1[tau], m, sum1);
            }
        }
        unsigned long long m0 = packkey(sum0, tid);
        unsigned long long m1 = packkey(sum1, tid + 256);
        unsigned long long m = (m1 < m0) ? m1 : m0;
        for (int o = 32; o; o >>= 1) {
            unsigned long long o2 = __shfl_down(m, o, 64);
            if (o2 < m) m = o2;
        }
        if (lane == 0) red[w] = m;
        __syncthreads();
        if (tid == 0) {
            unsigned long long b = red[0];
            #pragma unroll
            for (int i = 1; i < 4; ++i) if (red[i] < b) b = red[i];
            int sv = (int)(b & 0xFFFFFFFFull);
            sCur = sv;  keys[t] = sv;
        }
        __syncthreads();
    }

    // ---- output: [sofar(32) | pls(B,TL,J)] ----
    int s16 = keys[TLn], s15 = keys[TLn - 1];
    float v[8];
    #pragma unroll
    for (int q = 0; q < 8; ++q)                  // 8 independent gathers in flight
        v[q] = PLT[(size_t)(q * 256 + tid) * Cn + s15];
    if (tid < Bn) out[tid] = (float)s16;
    #pragma unroll
    for (int q = 0; q < 8; ++q)
        for (int b = 0; b < Bn; ++b)             // 256B contiguous per store inst
            out[Bn + (size_t)b * (TLn * Jd) + q * 256 + tid] = v[q];
}

extern "C" void kernel_launch(void* const* d_in, const int* in_sizes, int n_in,
                              void* d_out, int out_size, void* d_ws, size_t ws_size,
                              hipStream_t stream) {
    // inputs: 0:x (dead, 32MB), 1:lens (dead), 2:sos, 3:label_seqs, 4:W  (all f32)
    const float* sos = (const float*)d_in[2];
    const float* L   = (const float*)d_in[3];
    const float* W   = (const float*)d_in[4];
    float* out = (float*)d_out;

    // ws: S0(2KB)@0 | l2T(32KB)@4K | PLT(4MB)@64K | LT(4MB) | DOT(16.8MB)
    const size_t l2Off  = 4096;
    const size_t pltOff = 65536;
    const size_t ltOff  = pltOff + (size_t)TLn * Jd * Cn * sizeof(float);
    const size_t dotOff = ltOff  + (size_t)TLn * Jd * Cn * sizeof(float);
    const size_t need   = dotOff + (size_t)Cn * TLn * Cn * sizeof(float);  // ~25 MB
    char* base = (ws_size >= need) ? (char*)d_ws : (char*)d_in[0];  // x dead, 32 MB
    float* S0   = (float*)base;
    float* l2T  = (float*)(base + l2Off);
    float* PLT  = (float*)(base + pltOff);
    float* LT   = (float*)(base + ltOff);
    float* DOT  = (float*)(base + dotOff);

    hipLaunchKernelGGL(k_prep3, dim3(512), dim3(256), 0, stream, L, W, LT, l2T, PLT);
    hipLaunchKernelGGL(k_dot,   dim3(513), dim3(256), 0, stream,
                       LT, PLT, l2T, sos, W, DOT, S0);
    hipLaunchKernelGGL(k_fin,   dim3(1),   dim3(256), 0, stream, S0, DOT, PLT, out);
}

// Round 12
// 122.264 us; speedup vs baseline: 1.4333x; 1.0231x over previous
//
#include <hip/hip_runtime.h>

// Problem constants
#define Jd   128   // feature dim
#define Cn   512   // num classes
#define TLn  16    // label seq length
#define Bn   32    // batch

// ---------------------------------------------------------------------------
// Reduction (x, lens dead; batch-uniform trajectory):
//   LT [tau][k][c] = L[c,tau,k]          l2T[tau][c] = ||L[c,tau,:]||^2
//   PLT[tau][j][c] = sum_k W[k][j]*L[c,tau,k]          ( = (L@W)^T )
//   S0[c]          = ||sos@W - L[c,0,:]||^2
//   DOT[s][tau][c] = l2T[tau][c] - 2*sum_j PLT[tau][j][s]*LT[tau][j][c]
//   s_0 = argmin S0;  s_t = argmin_c sum_{tau<t} DOT[s_{t-1}][tau][c]
//   out = [ broadcast_B(s_16) | broadcast_B(PLT[:, :, s_15]) ]
// Round-11 accounting: fill 42us + restore ~8us are harness-fixed; mine ~75us
// = k_dot ~23 + prep3 ~5 + k_fin ~13 + gaps. This round: (a) k_dot 2->3
// blocks/CU (48KB LDS x3 = 144 <= 160KB; the barrier-drain between staging
// phases gets a third block to hide behind); (b) un-fuse the 262KB output
// store from the 1-block chain (one CU's store path was serializing it) ->
// wide k_out. No arithmetic change anywhere -> absmax stays 0.
// ---------------------------------------------------------------------------

__device__ __forceinline__ unsigned int f2ord(float f) {
    unsigned int u = __float_as_uint(f);
    return (u & 0x80000000u) ? ~u : (u | 0x80000000u);   // monotone total order
}
__device__ __forceinline__ unsigned long long packkey(float v, int c) {
    return ((unsigned long long)f2ord(v) << 32) | (unsigned int)c;
}

// grid = 512 x 256: bid -> tau = bid&15, jh = (bid>>4)&1 (j-half), ct = bid>>5
// (16 c-tiles of 32). Produces PLT[tau][jh*64..+63][c-tile]; jh==0 blocks also
// emit LT + l2T for their c-tile.
__global__ void __launch_bounds__(256, 4)
k_prep3(const float* __restrict__ L, const float* __restrict__ W,
        float* __restrict__ LT, float* __restrict__ l2T,
        float* __restrict__ PLT) {
    __shared__ float Lst[128][36];               // 18 KB transposed L tile [k][c]
    __shared__ float Ws[128][68];                // 34 KB W half [k][j-j0]
    int tid = threadIdx.x, bid = blockIdx.x;
    int tau = bid & 15, jh = (bid >> 4) & 1, c0 = (bid >> 5) * 32;
    int j0 = jh * 64;

    // --- stage Lst (transpose 32 L-rows; coalesced global reads) + l2 ---
    int cr = tid >> 3, oc = tid & 7;             // c-row 0..31, octant
    const float4* src = (const float4*)(L + ((size_t)(c0 + cr) * TLn + tau) * Jd);
    float l2p = 0.f;
    #pragma unroll
    for (int i = 0; i < 4; ++i) {
        float4 v = src[oc * 4 + i];
        int kb = (oc * 4 + i) * 4;
        Lst[kb + 0][cr] = v.x;  Lst[kb + 1][cr] = v.y;
        Lst[kb + 2][cr] = v.z;  Lst[kb + 3][cr] = v.w;
        l2p += v.x * v.x + v.y * v.y + v.z * v.z + v.w * v.w;
    }
    l2p += __shfl_down(l2p, 4, 8);               // reduce over octant (8 lanes/c)
    l2p += __shfl_down(l2p, 2, 8);
    l2p += __shfl_down(l2p, 1, 8);
    if (oc == 0 && jh == 0) l2T[tau * Cn + c0 + cr] = l2p;

    // --- stage Ws: W[k][j0..j0+63], straight coalesced copy ---
    #pragma unroll
    for (int r = 0; r < 8; ++r) {
        int idx = r * 256 + tid;                 // 0..2047 float4s
        int k = idx >> 4, f = idx & 15;
        *(float4*)&Ws[k][f * 4] = *(const float4*)(W + (size_t)k * Jd + j0 + f * 4);
    }
    __syncthreads();

    int c = tid & 31, jq = tid >> 5;             // c lane (coalesced), 8 j-groups

    // --- LT emit (jh==0 only): b32 reads conflict-free, 128B-chunk stores ---
    if (jh == 0) {
        #pragma unroll
        for (int k = jq; k < Jd; k += 8)
            LT[((size_t)tau * Jd + k) * Cn + c0 + c] = Lst[k][c];
    }

    // --- GEMM: PLT[tau][j0+jq*8+i][c0+c] = sum_k Ws[k][jq*8+i] * Lst[k][c] ---
    float acc[8] = {};
    #pragma unroll 4
    for (int k = 0; k < Jd; ++k) {               // ascending k: same sum order
        float a = Lst[k][c];                     // b32, banks all distinct (pitch 36)
        float4 w0 = *(const float4*)&Ws[k][jq * 8];      // 32-lane broadcast b128
        float4 w1 = *(const float4*)&Ws[k][jq * 8 + 4];
        acc[0] = fmaf(a, w0.x, acc[0]);
        acc[1] = fmaf(a, w0.y, acc[1]);
        acc[2] = fmaf(a, w0.z, acc[2]);
        acc[3] = fmaf(a, w0.w, acc[3]);
        acc[4] = fmaf(a, w1.x, acc[4]);
        acc[5] = fmaf(a, w1.y, acc[5]);
        acc[6] = fmaf(a, w1.z, acc[6]);
        acc[7] = fmaf(a, w1.w, acc[7]);
    }
    #pragma unroll
    for (int i = 0; i < 8; ++i)                  // two 128B chunks per store inst
        PLT[((size_t)tau * Jd + j0 + jq * 8 + i) * Cn + c0 + c] = acc[i];
}

// grid = 513 x 256, LDS-staged GEMM, 3 blocks/CU (144KB LDS). bid<512:
// tau = bid&15, st = (bid>>4)&7 (64 s), cq = bid>>7 (128 c). K in 2 j-halves;
// micro 4s x 8c. bid==512: S0.
__global__ void __launch_bounds__(256, 3)
k_dot(const float* __restrict__ LT, const float* __restrict__ PLT,
      const float* __restrict__ l2T,
      const float* __restrict__ sos, const float* __restrict__ W,
      float* __restrict__ DOT, float* __restrict__ S0) {
    __shared__ float As[64][64];                 // 16 KB  [j][s]
    __shared__ float Bs[64][128];                // 32 KB  [j][c]
    int tid = threadIdx.x, bid = blockIdx.x;

    if (bid == 512) {                            // ---- S0 path ----
        float* pred0 = &As[0][0];
        if (tid < Jd) {
            float a = 0.f;
            for (int k = 0; k < Jd; ++k) a = fmaf(sos[k], W[k * Jd + tid], a);
            pred0[tid] = a;
        }
        __syncthreads();
        float a0 = 0.f, a1 = 0.f;
        for (int jj = 0; jj < Jd; ++jj) {
            float p = pred0[jj];
            float d0 = p - LT[(size_t)jj * Cn + tid];        // tau = 0 plane
            float d1 = p - LT[(size_t)jj * Cn + tid + 256];
            a0 = fmaf(d0, d0, a0);
            a1 = fmaf(d1, d1, a1);
        }
        S0[tid] = a0;  S0[tid + 256] = a1;
        return;
    }

    int tau = bid & 15, st = (bid >> 4) & 7, cq = bid >> 7;
    int s0 = st * 64, c0 = cq * 128;
    int sg = tid >> 4, cg = tid & 15;            // 16x16 threads

    float acc[4][8] = {};                        // 4 s x (4+4) c
    for (int h = 0; h < 2; ++h) {                // j-halves
        __syncthreads();
        // stage A half: 64 j-rows x 64 s  (coalesced global, conflict-free LDS)
        const float4* Asrc = (const float4*)(PLT + ((size_t)tau * Jd + h * 64) * Cn + s0);
        #pragma unroll
        for (int i = 0; i < 4; ++i) {
            int flat = i * 256 + tid;            // 0..1023 float4s
            int row = flat >> 4, col = flat & 15;
            *(float4*)&As[row][col * 4] = Asrc[(size_t)row * (Cn / 4) + col];
        }
        // stage B half: 64 j-rows x 128 c
        const float4* Bsrc = (const float4*)(LT + ((size_t)tau * Jd + h * 64) * Cn + c0);
        #pragma unroll
        for (int i = 0; i < 8; ++i) {
            int flat = i * 256 + tid;            // 0..2047 float4s
            int row = flat >> 5, col = flat & 31;
            *(float4*)&Bs[row][col * 4] = Bsrc[(size_t)row * (Cn / 4) + col];
        }
        __syncthreads();
        #pragma unroll 4
        for (int j = 0; j < 64; ++j) {           // ascending j: same sum order
            float4 a  = *(const float4*)&As[j][sg * 4];       // broadcast, no conflict
            float4 b0 = *(const float4*)&Bs[j][cg * 4];       // 2-way (free)
            float4 b1 = *(const float4*)&Bs[j][64 + cg * 4];  // 2-way (free)
            float av[4] = {a.x, a.y, a.z, a.w};
            float bv[8] = {b0.x, b0.y, b0.z, b0.w, b1.x, b1.y, b1.z, b1.w};
            #pragma unroll
            for (int i = 0; i < 4; ++i)
                #pragma unroll
                for (int q = 0; q < 8; ++q)
                    acc[i][q] = fmaf(av[i], bv[q], acc[i][q]);
        }
    }

    float4 l2a = *(const float4*)(l2T + tau * Cn + c0 + cg * 4);
    float4 l2b = *(const float4*)(l2T + tau * Cn + c0 + 64 + cg * 4);
    #pragma unroll
    for (int i = 0; i < 4; ++i) {
        int s = s0 + sg * 4 + i;
        float* dst = DOT + ((size_t)s * TLn + tau) * Cn + c0;
        float4 v0 = {l2a.x - 2.f * acc[i][0], l2a.y - 2.f * acc[i][1],
                     l2a.z - 2.f * acc[i][2], l2a.w - 2.f * acc[i][3]};
        float4 v1 = {l2b.x - 2.f * acc[i][4], l2b.y - 2.f * acc[i][5],
                     l2b.z - 2.f * acc[i][6], l2b.w - 2.f * acc[i][7]};
        *(float4*)(dst + cg * 4) = v0;           // 256B contiguous per 16 lanes
        *(float4*)(dst + 64 + cg * 4) = v1;
    }
}

// 1 block x 256: 17-step argmin chain only (32 loads in flight per step,
// mask-FMA); writes the 17 keys to global.
__global__ void k_seq(const float* __restrict__ S0, const float* __restrict__ DOT,
                      int* __restrict__ keys) {
    __shared__ unsigned long long red[4];
    __shared__ int sCur;
    int tid = threadIdx.x, w = tid >> 6, lane = tid & 63;

    for (int t = 0; t <= TLn; ++t) {
        float sum0, sum1;
        if (t == 0) {
            sum0 = S0[tid];  sum1 = S0[tid + 256];
        } else {
            const float* base = DOT + (size_t)sCur * TLn * Cn;
            float v0[TLn], v1[TLn];
            #pragma unroll
            for (int tau = 0; tau < TLn; ++tau) {            // 32 independent loads
                v0[tau] = base[(size_t)tau * Cn + tid];
                v1[tau] = base[(size_t)tau * Cn + tid + 256];
            }
            sum0 = sum1 = 0.f;
            #pragma unroll
            for (int tau = 0; tau < TLn; ++tau) {
                float m = (tau < t) ? 1.f : 0.f;
                sum0 = fmaf(v0[tau], m, sum0);
                sum1 = fmaf(v1[tau], m, sum1);
            }
        }
        unsigned long long m0 = packkey(sum0, tid);
        unsigned long long m1 = packkey(sum1, tid + 256);
        unsigned long long m = (m1 < m0) ? m1 : m0;
        for (int o = 32; o; o >>= 1) {
            unsigned long long o2 = __shfl_down(m, o, 64);
            if (o2 < m) m = o2;
        }
        if (lane == 0) red[w] = m;
        __syncthreads();
        if (tid == 0) {
            unsigned long long b = red[0];
            #pragma unroll
            for (int i = 1; i < 4; ++i) if (red[i] < b) b = red[i];
            int sv = (int)(b & 0xFFFFFFFFull);
            sCur = sv;  keys[t] = sv;
        }
        __syncthreads();
    }
}

// grid = 512 x 128: out = [sofar(32) | pls(B,TL,J)]; bt = b*TLn+tau.
// PLT gathers are L2-broadcast across the 32 b-copies; stores coalesced.
__global__ void k_out(const float* __restrict__ PLT, const int* __restrict__ keys,
                      float* __restrict__ out) {
    int bt = blockIdx.x, j = threadIdx.x, tau = bt & (TLn - 1);
    int s16 = keys[TLn], s15 = keys[TLn - 1];
    out[Bn + (size_t)bt * Jd + j] = PLT[((size_t)tau * Jd + j) * Cn + s15];
    if (bt == 0 && j < Bn) out[j] = (float)s16;
}

extern "C" void kernel_launch(void* const* d_in, const int* in_sizes, int n_in,
                              void* d_out, int out_size, void* d_ws, size_t ws_size,
                              hipStream_t stream) {
    // inputs: 0:x (dead, 32MB), 1:lens (dead), 2:sos, 3:label_seqs, 4:W  (all f32)
    const float* sos = (const float*)d_in[2];
    const float* L   = (const float*)d_in[3];
    const float* W   = (const float*)d_in[4];
    float* out = (float*)d_out;

    // ws: S0(2KB)@0 | keys@2048 | l2T(32KB)@4K | PLT(4MB)@64K | LT(4MB) | DOT(16.8MB)
    const size_t l2Off  = 4096;
    const size_t pltOff = 65536;
    const size_t ltOff  = pltOff + (size_t)TLn * Jd * Cn * sizeof(float);
    const size_t dotOff = ltOff  + (size_t)TLn * Jd * Cn * sizeof(float);
    const size_t need   = dotOff + (size_t)Cn * TLn * Cn * sizeof(float);  // ~25 MB
    char* base = (ws_size >= need) ? (char*)d_ws : (char*)d_in[0];  // x dead, 32 MB
    float* S0   = (float*)base;
    int*   keys = (int*)(base + 2048);
    float* l2T  = (float*)(base + l2Off);
    float* PLT  = (float*)(base + pltOff);
    float* LT   = (float*)(base + ltOff);
    float* DOT  = (float*)(base + dotOff);

    hipLaunchKernelGGL(k_prep3, dim3(512), dim3(256), 0, stream, L, W, LT, l2T, PLT);
    hipLaunchKernelGGL(k_dot,   dim3(513), dim3(256), 0, stream,
                       LT, PLT, l2T, sos, W, DOT, S0);
    hipLaunchKernelGGL(k_seq,   dim3(1),   dim3(256), 0, stream, S0, DOT, keys);
    hipLaunchKernelGGL(k_out,   dim3(Bn * TLn), dim3(Jd), 0, stream, PLT, keys, out);
}